// Round 5
// baseline (747.917 us; speedup 1.0000x reference)
//
#include <hip/hip_runtime.h>
#include <hip/hip_fp16.h>

typedef _Float16 half_t;
typedef _Float16 f16x8 __attribute__((ext_vector_type(8)));
typedef _Float16 f16x4 __attribute__((ext_vector_type(4)));
typedef float f32x4 __attribute__((ext_vector_type(4)));
typedef __attribute__((address_space(3))) half_t* lds_p;

#define SEQ 4096
#define DDIM 1024
#define NBATCH 4

// async global->LDS, 16B per lane. LDS dest is wave-uniform base + lane*16,
// so the per-lane lds pointer MUST be base + lane*16 in wave-lane order.
__device__ __forceinline__ void gload16(const half_t* g, half_t* l) {
  __builtin_amdgcn_global_load_lds((const __attribute__((address_space(1))) void*)g,
                                   (__attribute__((address_space(3))) void*)l, 16, 0, 0);
}

// asm ds_read_b128: opaque to SIInsertWaitcnts, so the compiler cannot insert
// a vmcnt(0) drain before it. Caller hand-places s_waitcnt lgkmcnt(0)
// + sched_barrier(0) before consuming (guide rule #18).
__device__ __forceinline__ f16x8 ds_read128(lds_p p) {
  f16x8 r;
  asm volatile("ds_read_b128 %0, %1" : "=v"(r) : "v"(p));
  return r;
}

// ---------------- fp32 -> fp16 elementwise convert ----------------
__global__ __launch_bounds__(256) void conv_f16(const float* __restrict__ src,
                                                half_t* __restrict__ dst) {
  int i = blockIdx.x * 256 + threadIdx.x;
  float4 x = ((const float4*)src)[i];
  f16x4 o = {(half_t)x.x, (half_t)x.y, (half_t)x.z, (half_t)x.w};
  *(f16x4*)(dst + (size_t)i * 4) = o;
}

// ------- enc [b][e][d] fp32 -> encF [b][e][d] f16 AND encT [b][d][e] f16 ----
__global__ __launch_bounds__(256) void transconv_f16(const float* __restrict__ src,
                                                     half_t* __restrict__ dstF,
                                                     half_t* __restrict__ dstT) {
  __shared__ float tile[32][33];
  int b = blockIdx.z;
  int e0 = blockIdx.x * 32, d0 = blockIdx.y * 32;
  const float* s = src + (size_t)b * SEQ * DDIM;
  half_t* df = dstF + (size_t)b * SEQ * DDIM;
  half_t* dt = dstT + (size_t)b * DDIM * SEQ;
  int tx = threadIdx.x & 31, ty = threadIdx.x >> 5;
#pragma unroll
  for (int i = 0; i < 4; i++) {
    int e = e0 + ty + i * 8;
    float v = s[(size_t)e * DDIM + d0 + tx];
    tile[ty + i * 8][tx] = v;
    df[(size_t)e * DDIM + d0 + tx] = (half_t)v;
  }
  __syncthreads();
#pragma unroll
  for (int i = 0; i < 4; i++) {
    int d = d0 + ty + i * 8;
    dt[(size_t)d * SEQ + e0 + tx] = (half_t)tile[tx][ty + i * 8];
  }
}

// ------ fp16 BT GEMM, 256x128 tile, 3-buffer counted-vmcnt pipeline --------
// C[M][N] = A[M][K]*B[N][K]^T.
// R5: T4 realized. R4 post-mortem: drain-0 at each K-step = chip-wide 16MiB
// synchronized burst (~10k cyc) -> m218's "8ph-with-drain0 ~= 1ph". Fix:
// 2-tile lookahead. 3 rotating LDS buffers (3 x 48 KiB = 144 KiB), per-tile
// loads/thread = 4(A)+2(B) = 6; steady-state end-of-step wait = vmcnt(6)
// (tile t+2's 6 loads stay in flight) -> loads NEVER fully drain in the main
// loop; memory streams continuously with ~2 tiles of slack.
// Sync audit: barrier at end of step t guarantees (a) every wave drained its
// ds_reads (lgkmcnt(0) pre-MFMA) -> buffer reused at t+1's stage is dead;
// (b) every wave waited vmcnt(6) -> tile t+1 fully in LDS (vmcnt retires
// in issue order, so count 6 isolates exactly tile t+1's completion).
// 512 thr = 8 waves (2Mx4N), per-wave 128x32 out (8x2 16x16 frags).
// XOR chunk swizzle (slot = chunk ^ (row&7)): bank conflicts measured 0.
// blockIdx.z: batch (sA/sB/sC strides) OR split-K chunk (atom=1 -> fp32
// atomic-add epilogue).
#define TM 256
#define TN 128
#define TK 64

__global__ __launch_bounds__(512, 2) void gemm_p3(const half_t* __restrict__ A,
                                                  const half_t* __restrict__ B,
                                                  float* __restrict__ C, int M, int N, int K,
                                                  int kc, long sA, long sB, long sC,
                                                  int atom) {
  A += (size_t)blockIdx.z * (size_t)sA;
  B += (size_t)blockIdx.z * (size_t)sB;
  C += (size_t)blockIdx.z * (size_t)sC;
  __shared__ __align__(16) half_t As[3][TM * TK];
  __shared__ __align__(16) half_t Bs[3][TN * TK];
  const int tid = threadIdx.x;
  const int wave = tid >> 6, lane = tid & 63;
  const int wm = (wave >> 2) * 128, wn = (wave & 3) * 32;  // 2x4 wave grid
  const int mrow = lane & 15, quad = lane >> 4;

  f32x4 acc[8][2];
#pragma unroll
  for (int i = 0; i < 8; i++)
#pragma unroll
    for (int j = 0; j < 2; j++) acc[i][j] = {0.f, 0.f, 0.f, 0.f};

  const half_t* Ag = A + (size_t)(blockIdx.x * TM) * K;
  const half_t* Bg = B + (size_t)(blockIdx.y * TN) * K;
  lds_p As3 = (lds_p)&As[0][0];
  lds_p Bs3 = (lds_p)&Bs[0][0];

  // staging: A = 256 rows x 8 chunks(16B) -> 4 loads/thr; B = 128 rows -> 2.
  // cid covers the tile collectively; row = cid>>3, slot = cid&7,
  // global chunk = slot^(row&7). LDS dest = base + cid*16B (lane-contiguous).
  auto stage = [&](int buf, int k0) {
#pragma unroll
    for (int i = 0; i < 4; i++) {
      int cid = i * 512 + tid;
      int row = cid >> 3, slot = cid & 7;
      int chunk = slot ^ (row & 7);
      gload16(Ag + (size_t)row * K + k0 + chunk * 8, &As[buf][row * TK + slot * 8]);
    }
#pragma unroll
    for (int i = 0; i < 2; i++) {
      int cid = i * 512 + tid;
      int row = cid >> 3, slot = cid & 7;
      int chunk = slot ^ (row & 7);
      gload16(Bg + (size_t)row * K + k0 + chunk * 8, &Bs[buf][row * TK + slot * 8]);
    }
  };

  const int nt = kc / TK;
  stage(0, 0);
  if (nt > 1) {
    stage(1, TK);
    asm volatile("s_waitcnt vmcnt(6)" ::: "memory");  // tile0 done, tile1 in flight
  } else {
    asm volatile("s_waitcnt vmcnt(0)" ::: "memory");
  }
  __builtin_amdgcn_s_barrier();

  int ib0 = 0, ib1 = 1, ib2 = 2;  // ib0 = buffer of tile t
  for (int t = 0; t < nt; ++t) {
    if (t + 2 < nt) stage(ib2, (t + 2) * TK);  // 2-tile lookahead
    lds_p Ab = As3 + ib0 * (TM * TK);
    lds_p Bb = Bs3 + ib0 * (TN * TK);
#pragma unroll
    for (int ks = 0; ks < 2; ks++) {
      f16x8 af[8], bf[2];
#pragma unroll
      for (int i = 0; i < 8; i++) {
        int ra = wm + i * 16 + mrow;
        int sa = (ks * 4 + quad) ^ (ra & 7);
        af[i] = ds_read128(Ab + ra * TK + sa * 8);
      }
#pragma unroll
      for (int j = 0; j < 2; j++) {
        int rb = wn + j * 16 + mrow;
        int sb = (ks * 4 + quad) ^ (rb & 7);
        bf[j] = ds_read128(Bb + rb * TK + sb * 8);
      }
      asm volatile("s_waitcnt lgkmcnt(0)" ::: "memory");
      __builtin_amdgcn_sched_barrier(0);  // rule #18: keep MFMA below the wait
#pragma unroll
      for (int mi = 0; mi < 8; mi++)
#pragma unroll
        for (int ni = 0; ni < 2; ni++)
          acc[mi][ni] =
              __builtin_amdgcn_mfma_f32_16x16x32_f16(af[mi], bf[ni], acc[mi][ni], 0, 0, 0);
    }
    if (t + 1 < nt) {
      // counted wait: tile t+1 must be resident; tile t+2 may stay in flight.
      if (t + 2 < nt)
        asm volatile("s_waitcnt vmcnt(6)" ::: "memory");
      else
        asm volatile("s_waitcnt vmcnt(0)" ::: "memory");
      __builtin_amdgcn_s_barrier();
    }
    int tmp = ib0;
    ib0 = ib1;
    ib1 = ib2;
    ib2 = tmp;
  }
  // epilogue: D[row=(quad*4+r)][col=lane&15] per 16x16 tile [m89/m91]
#pragma unroll
  for (int mi = 0; mi < 8; mi++) {
#pragma unroll
    for (int ni = 0; ni < 2; ni++) {
      int row0 = blockIdx.x * TM + wm + mi * 16 + quad * 4;
      int col = blockIdx.y * TN + wn + ni * 16 + mrow;
      float* Cp = C + (size_t)row0 * N + col;
      if (atom) {
#pragma unroll
        for (int r = 0; r < 4; r++) unsafeAtomicAdd(Cp + (size_t)r * N, acc[mi][ni][r]);
      } else {
#pragma unroll
        for (int r = 0; r < 4; r++) Cp[(size_t)r * N] = acc[mi][ni][r];
      }
    }
  }
}

// ---------------- row softmax: S[row][:] fp32 -> P[row][:] fp16 ----------------
__global__ __launch_bounds__(256) void softmax_rows(const float* __restrict__ S,
                                                    half_t* __restrict__ P) {
  const int row = blockIdx.x;
  const float4* Sr = (const float4*)(S + (size_t)row * SEQ);
  const int tid = threadIdx.x, lane = tid & 63, wave = tid >> 6;
  __shared__ float red[4];
  __shared__ float bc;
  float4 v[4];
  float m = -1e30f;
#pragma unroll
  for (int j = 0; j < 4; j++) {
    v[j] = Sr[tid + j * 256];
    m = fmaxf(m, fmaxf(fmaxf(v[j].x, v[j].y), fmaxf(v[j].z, v[j].w)));
  }
#pragma unroll
  for (int o = 32; o; o >>= 1) m = fmaxf(m, __shfl_xor(m, o));
  if (lane == 0) red[wave] = m;
  __syncthreads();
  if (tid == 0) bc = fmaxf(fmaxf(red[0], red[1]), fmaxf(red[2], red[3]));
  __syncthreads();
  m = bc;
  float s = 0.f;
#pragma unroll
  for (int j = 0; j < 4; j++) {
    v[j].x = __expf(v[j].x - m);
    v[j].y = __expf(v[j].y - m);
    v[j].z = __expf(v[j].z - m);
    v[j].w = __expf(v[j].w - m);
    s += v[j].x + v[j].y + v[j].z + v[j].w;
  }
#pragma unroll
  for (int o = 32; o; o >>= 1) s += __shfl_xor(s, o);
  __syncthreads();
  if (lane == 0) red[wave] = s;
  __syncthreads();
  if (tid == 0) bc = red[0] + red[1] + red[2] + red[3];
  __syncthreads();
  float r = 1.0f / bc;
  f16x4* Pr = (f16x4*)(P + (size_t)row * SEQ);
#pragma unroll
  for (int j = 0; j < 4; j++) {
    f16x4 o = {(half_t)(v[j].x * r), (half_t)(v[j].y * r), (half_t)(v[j].z * r),
               (half_t)(v[j].w * r)};
    Pr[tid + j * 256] = o;
  }
}

// ---------------- naive fp32 fallback (no workspace needed) ----------------
__global__ __launch_bounds__(256) void naive_attn(const float* __restrict__ enc,
                                                  const float* __restrict__ dec,
                                                  float* __restrict__ out) {
  const int b = blockIdx.y, t = blockIdx.x;
  const float* encb = enc + (size_t)b * SEQ * DDIM;
  const float* q = dec + ((size_t)b * SEQ + t) * DDIM;
  __shared__ float qs[DDIM];
  __shared__ float sc[SEQ];
  __shared__ float red[4];
  __shared__ float bc;
  const int tid = threadIdx.x, lane = tid & 63, wave = tid >> 6;
  for (int i = tid; i < DDIM; i += 256) qs[i] = q[i];
  __syncthreads();
  for (int e = tid; e < SEQ; e += 256) {
    const float* er = encb + (size_t)e * DDIM;
    float s = 0.f;
    for (int d = 0; d < DDIM; d += 4) {
      float4 ev = *(const float4*)(er + d);
      s += ev.x * qs[d] + ev.y * qs[d + 1] + ev.z * qs[d + 2] + ev.w * qs[d + 3];
    }
    sc[e] = s;
  }
  __syncthreads();
  float m = -1e30f;
  for (int e = tid; e < SEQ; e += 256) m = fmaxf(m, sc[e]);
#pragma unroll
  for (int o = 32; o; o >>= 1) m = fmaxf(m, __shfl_xor(m, o));
  if (lane == 0) red[wave] = m;
  __syncthreads();
  if (tid == 0) bc = fmaxf(fmaxf(red[0], red[1]), fmaxf(red[2], red[3]));
  __syncthreads();
  m = bc;
  float s = 0.f;
  for (int e = tid; e < SEQ; e += 256) {
    float p = __expf(sc[e] - m);
    sc[e] = p;
    s += p;
  }
#pragma unroll
  for (int o = 32; o; o >>= 1) s += __shfl_xor(s, o);
  __syncthreads();
  if (lane == 0) red[wave] = s;
  __syncthreads();
  if (tid == 0) bc = red[0] + red[1] + red[2] + red[3];
  __syncthreads();
  const float rinv = 1.0f / bc;
  const int d0 = tid * 4;
  float4 acc = {0.f, 0.f, 0.f, 0.f};
  for (int e = 0; e < SEQ; e++) {
    float p = sc[e];
    float4 ev = *(const float4*)(encb + (size_t)e * DDIM + d0);
    acc.x += p * ev.x;
    acc.y += p * ev.y;
    acc.z += p * ev.z;
    acc.w += p * ev.w;
  }
  float4* o4 = (float4*)(out + ((size_t)b * SEQ + t) * DDIM + d0);
  float4 res = {acc.x * rinv, acc.y * rinv, acc.z * rinv, acc.w * rinv};
  *o4 = res;
}

extern "C" void kernel_launch(void* const* d_in, const int* in_sizes, int n_in, void* d_out,
                              int out_size, void* d_ws, size_t ws_size, hipStream_t stream) {
  const float* enc = (const float*)d_in[0];
  const float* dec = (const float*)d_in[1];
  float* out = (float*)d_out;

  const size_t SZ_S = (size_t)SEQ * SEQ * 4;            // 64 MiB (one batch)
  const size_t SZ_P = (size_t)SEQ * SEQ * 2;            // 32 MiB (one batch)
  const size_t SZ_H = (size_t)NBATCH * SEQ * DDIM * 2;  // 32 MiB each
  const size_t NEED = SZ_S + SZ_P + 3 * SZ_H;           // 192 MiB (proven R0-R4)

  const int nconv = NBATCH * SEQ * DDIM / 4 / 256;  // 16384 blocks

  if (ws_size >= NEED) {
    char* w = (char*)d_ws;
    float* S = (float*)w;
    half_t* P = (half_t*)(w + SZ_S);
    half_t* decF = (half_t*)(w + SZ_S + SZ_P);
    half_t* encF = (half_t*)(w + SZ_S + SZ_P + SZ_H);
    half_t* encT = (half_t*)(w + SZ_S + SZ_P + 2 * SZ_H);

    hipMemsetAsync(out, 0, (size_t)NBATCH * SEQ * DDIM * 4, stream);
    conv_f16<<<nconv, 256, 0, stream>>>(dec, decF);
    transconv_f16<<<dim3(SEQ / 32, DDIM / 32, NBATCH), 256, 0, stream>>>(enc, encF, encT);

    for (int b = 0; b < NBATCH; b++) {
      const size_t eo = (size_t)b * SEQ * DDIM;
      // S[t][e] = dec[t]·enc[e]; grid 16x32 = 512 blocks
      gemm_p3<<<dim3(SEQ / TM, SEQ / TN, 1), 512, 0, stream>>>(
          decF + eo, encF + eo, S, SEQ, SEQ, DDIM, DDIM, 0, 0, 0, 0);
      softmax_rows<<<SEQ, 256, 0, stream>>>(S, P);
      // out[t][d] += sum_{e in chunk z} P[t][e]*encT[d][e]; split-K z=4:
      // grid 16x8x4 = 512 blocks, fp32 atomic epilogue
      gemm_p3<<<dim3(SEQ / TM, DDIM / TN, 4), 512, 0, stream>>>(
          P, encT + (size_t)b * DDIM * SEQ, out + eo, SEQ, DDIM, SEQ, SEQ / 4, SEQ / 4,
          SEQ / 4, 0, 1);
    }
  } else {
    naive_attn<<<dim3(SEQ, NBATCH), 256, 0, stream>>>(enc, dec, out);
  }
}

// Round 6
// 694.079 us; speedup vs baseline: 1.0776x; 1.0776x over previous
//
#include <hip/hip_runtime.h>
#include <hip/hip_fp16.h>

typedef _Float16 half_t;
typedef _Float16 f16x8 __attribute__((ext_vector_type(8)));
typedef _Float16 f16x4 __attribute__((ext_vector_type(4)));
typedef float f32x4 __attribute__((ext_vector_type(4)));
typedef __attribute__((address_space(3))) half_t* lds_p;

#define SEQ 4096
#define DDIM 1024
#define NBATCH 4

// async global->LDS, 16B per lane. LDS dest is wave-uniform base + lane*16.
__device__ __forceinline__ void gload16(const half_t* g, half_t* l) {
  __builtin_amdgcn_global_load_lds((const __attribute__((address_space(1))) void*)g,
                                   (__attribute__((address_space(3))) void*)l, 16, 0, 0);
}

// asm ds_read_b128: opaque to SIInsertWaitcnts (no spurious vmcnt drains).
// Caller hand-places s_waitcnt lgkmcnt(0) + sched_barrier(0) (rule #18).
__device__ __forceinline__ f16x8 ds_read128(lds_p p) {
  f16x8 r;
  asm volatile("ds_read_b128 %0, %1" : "=v"(r) : "v"(p));
  return r;
}

// ---------------- fp32 -> fp16 elementwise convert ----------------
__global__ __launch_bounds__(256) void conv_f16(const float* __restrict__ src,
                                                half_t* __restrict__ dst) {
  int i = blockIdx.x * 256 + threadIdx.x;
  float4 x = ((const float4*)src)[i];
  f16x4 o = {(half_t)x.x, (half_t)x.y, (half_t)x.z, (half_t)x.w};
  *(f16x4*)(dst + (size_t)i * 4) = o;
}

// ------- enc [b][e][d] fp32 -> encF [b][e][d] f16 AND encT [b][d][e] f16 ----
__global__ __launch_bounds__(256) void transconv_f16(const float* __restrict__ src,
                                                     half_t* __restrict__ dstF,
                                                     half_t* __restrict__ dstT) {
  __shared__ float tile[32][33];
  int b = blockIdx.z;
  int e0 = blockIdx.x * 32, d0 = blockIdx.y * 32;
  const float* s = src + (size_t)b * SEQ * DDIM;
  half_t* df = dstF + (size_t)b * SEQ * DDIM;
  half_t* dt = dstT + (size_t)b * DDIM * SEQ;
  int tx = threadIdx.x & 31, ty = threadIdx.x >> 5;
#pragma unroll
  for (int i = 0; i < 4; i++) {
    int e = e0 + ty + i * 8;
    float v = s[(size_t)e * DDIM + d0 + tx];
    tile[ty + i * 8][tx] = v;
    df[(size_t)e * DDIM + d0 + tx] = (half_t)v;
  }
  __syncthreads();
#pragma unroll
  for (int i = 0; i < 4; i++) {
    int d = d0 + ty + i * 8;
    dt[(size_t)d * SEQ + e0 + tx] = (half_t)tile[tx][ty + i * 8];
  }
}

// ===== fp16 BT GEMM, 256x256 tile, 8-PHASE schedule (guide §5 template) =====
// C[M][N] = A[M][K]*B[N][K]^T. R6: port of the proven 8-phase interleave
// (m196/m218/m248: 8ph+swz+setprio = 848 TF @ 256^2 K=1024 vs 666 2ph).
// R5 post-mortem: all monolithic schedules stall ~5k cyc/K-step because the
// whole CU alternates {LDS-read phase}->{MFMA phase} in lockstep; the 8-phase
// splits each K-tile into 4 quadrant phases so wave-level ds_read/stage/MFMA
// overlap within the CU, with counted vmcnt(4) only twice per iteration.
//
// Geometry: 8 waves (2Mx4N), per-wave 128x64 out = acc[8][4] f32x4.
// LDS: A = [2buf][256][64], B same, 128 KiB. Half-tile = 128 rows (16 KiB,
// 2 gloads/thread). K-tile t -> buf t&1.
// Per K-tile quadrant phases (per wave): P0: read A-low(8)+B-n0(4), MFMA
// q(m0,n0); P1: read B-n1(4), q(m0,n1); P2: read A-high(8), q(m1,n1);
// P3: no reads, q(m1,n0) (fb0 held since P0).
// Region deaths (all waves, via phase-end lgkm(0)+barrier): buf.B dies after
// P1; buf.A dies after P2. Stage schedule per iter i (tiles t0=2i,t1=2i+1):
//   p1:A0(t1) p2:A1(t1) [buf1.A died prev p7]
//   p3:B0(t0+2) p4:B1(t0+2) [buf0.B died p2]
//   p5:A0(t0+2) p6:A1(t0+2) [buf0.A died p3]
//   p7:B0(t1+2) p8:B1(t1+2) [buf1.B died p6]
// Checkpoints (issue order => retire order): p4: vmcnt(4) retires through
// A1(t1) -> tile t1 resident for p5; p8: vmcnt(4) retires through A1(t0+2)
// -> tile t0+2 resident for next p1. Steady state never drains to 0 (T4).
// Prologue: B0/B1/A0/A1(0), B0/B1(1), vmcnt(4) -> tile0 resident, tile1's
// B-halves in flight. XOR chunk swizzle kept (conflicts measured 0).
// blockIdx.z: batch (sA/sB/sC elem strides) OR split-K chunk (atom=1 ->
// fp32 atomic-add epilogue).
#define TM 256
#define TN 256
#define TK 64

#define SYNC_PRE()                                     \
  do {                                                 \
    __builtin_amdgcn_s_barrier();                      \
    __builtin_amdgcn_sched_barrier(0);                 \
    asm volatile("s_waitcnt lgkmcnt(0)" ::: "memory"); \
    __builtin_amdgcn_sched_barrier(0);                 \
    __builtin_amdgcn_s_setprio(1);                     \
  } while (0)
#define SYNC_POST()                    \
  do {                                 \
    __builtin_amdgcn_s_setprio(0);     \
    __builtin_amdgcn_s_barrier();      \
    __builtin_amdgcn_sched_barrier(0); \
  } while (0)
// 16 MFMA = one C-quadrant (4m x 2n x 2ks)
#define QMMA(qm, qn, FB)                                                             \
  {                                                                                  \
    _Pragma("unroll") for (int j = 0; j < 4; j++) {                                  \
      _Pragma("unroll") for (int jn = 0; jn < 2; jn++) {                             \
        acc[(qm)*4 + j][(qn)*2 + jn] = __builtin_amdgcn_mfma_f32_16x16x32_f16(       \
            fa[j][0], FB[jn][0], acc[(qm)*4 + j][(qn)*2 + jn], 0, 0, 0);             \
        acc[(qm)*4 + j][(qn)*2 + jn] = __builtin_amdgcn_mfma_f32_16x16x32_f16(       \
            fa[j][1], FB[jn][1], acc[(qm)*4 + j][(qn)*2 + jn], 0, 0, 0);             \
      }                                                                              \
    }                                                                                \
  }

__global__ __launch_bounds__(512, 2) void gemm8p(const half_t* __restrict__ A,
                                                 const half_t* __restrict__ B,
                                                 float* __restrict__ C, int M, int N, int K,
                                                 int kc, long sA, long sB, long sC, int atom) {
  A += (size_t)blockIdx.z * (size_t)sA;
  B += (size_t)blockIdx.z * (size_t)sB;
  C += (size_t)blockIdx.z * (size_t)sC;
  __shared__ __align__(16) half_t Ls[65536];  // A:[0,32768) B:[32768,65536)
  const int tid = threadIdx.x;
  const int wave = tid >> 6, lane = tid & 63;
  const int wm = (wave >> 2) * 128, wn = (wave & 3) * 64;
  const int mrow = lane & 15, quad = lane >> 4;
  const int sw0 = quad ^ (mrow & 7);

  f32x4 acc[8][4];
#pragma unroll
  for (int i = 0; i < 8; i++)
#pragma unroll
    for (int j = 0; j < 4; j++) acc[i][j] = {0.f, 0.f, 0.f, 0.f};

  const half_t* Ag = A + (size_t)(blockIdx.x * TM) * K;
  const half_t* Bg = B + (size_t)(blockIdx.y * TN) * K;
  lds_p L3 = (lds_p)&Ls[0];

  // staging: half-tile = 128 rows x 8 chunks(16B); 2 loads/thread.
  // row = cid>>3 (cid = i*512+tid), slot = cid&7, global chunk = slot^(row&7)
  const int row0 = tid >> 3, slot = tid & 7;
  const int chunk = slot ^ (row0 & 7);
  const size_t gOffA0 = (size_t)row0 * K + chunk * 8;
  const size_t gOffA1 = gOffA0 + (size_t)64 * K;  // row0+64: same chunk (64%8==0)
  const int lOff0 = row0 * 64 + slot * 8, lOff1 = lOff0 + 4096;

  auto stA = [&](int tt, int h) {
    size_t go = (size_t)tt * TK + (size_t)h * 128 * K;
    int lo = (tt & 1) * 16384 + h * 8192;
    gload16(Ag + go + gOffA0, &Ls[lo + lOff0]);
    gload16(Ag + go + gOffA1, &Ls[lo + lOff1]);
  };
  auto stB = [&](int tt, int h) {
    size_t go = (size_t)tt * TK + (size_t)h * 128 * K;
    int lo = 32768 + (tt & 1) * 16384 + h * 8192;
    gload16(Bg + go + gOffA0, &Ls[lo + lOff0]);
    gload16(Bg + go + gOffA1, &Ls[lo + lOff1]);
  };
  // fragment reads: row r in [0,256), elem = buf*16384 + r*64 + slot(ks)*8
  auto rdA = [&](int b, int m, int ks) {
    return ds_read128(L3 + b * 16384 + (wm + m * 16 + mrow) * 64 + ((ks * 4) ^ sw0) * 8);
  };
  auto rdB = [&](int b, int n, int ks) {
    return ds_read128(L3 + 32768 + b * 16384 + (wn + n * 16 + mrow) * 64 +
                      ((ks * 4) ^ sw0) * 8);
  };

  const int nt = kc / TK;  // 16 here (even)
  const int niter = nt / 2;
  // prologue: tile0 fully, tile1's B halves; vmcnt(4) -> tile0 resident
  stB(0, 0);
  stB(0, 1);
  stA(0, 0);
  stA(0, 1);
  stB(1, 0);
  stB(1, 1);
  asm volatile("s_waitcnt vmcnt(4)" ::: "memory");
  __builtin_amdgcn_s_barrier();
  __builtin_amdgcn_sched_barrier(0);

  f16x8 fa[4][2], fb0[2][2], fb1[2][2];
  for (int i = 0; i < niter; ++i) {
    const int t0 = 2 * i, t1 = t0 + 1;
    // p1: reads A-low(t0)+B-n0(t0); stage A0(t1)
#pragma unroll
    for (int j = 0; j < 4; j++) {
      fa[j][0] = rdA(0, j, 0);
      fa[j][1] = rdA(0, j, 1);
    }
#pragma unroll
    for (int jn = 0; jn < 2; jn++) {
      fb0[jn][0] = rdB(0, jn, 0);
      fb0[jn][1] = rdB(0, jn, 1);
    }
    stA(t1, 0);
    SYNC_PRE();
    QMMA(0, 0, fb0);
    SYNC_POST();
    // p2: reads B-n1(t0); stage A1(t1)
#pragma unroll
    for (int jn = 0; jn < 2; jn++) {
      fb1[jn][0] = rdB(0, 2 + jn, 0);
      fb1[jn][1] = rdB(0, 2 + jn, 1);
    }
    stA(t1, 1);
    SYNC_PRE();
    QMMA(0, 1, fb1);
    SYNC_POST();
    // p3: reads A-high(t0); stage B0(t0+2) [buf0.B died after p2]
#pragma unroll
    for (int j = 0; j < 4; j++) {
      fa[j][0] = rdA(0, 4 + j, 0);
      fa[j][1] = rdA(0, 4 + j, 1);
    }
    if (t0 + 2 < nt) stB(t0 + 2, 0);
    SYNC_PRE();
    QMMA(1, 1, fb1);
    SYNC_POST();
    // p4: stage B1(t0+2); CHECKPOINT (retires through A1(t1) -> t1 resident)
    if (t0 + 2 < nt) {
      stB(t0 + 2, 1);
      asm volatile("s_waitcnt vmcnt(4)" ::: "memory");
    } else {
      asm volatile("s_waitcnt vmcnt(0)" ::: "memory");
    }
    SYNC_PRE();
    QMMA(1, 0, fb0);
    SYNC_POST();
    // p5: reads A-low(t1)+B-n0(t1); stage A0(t0+2) [buf0.A died after p3]
#pragma unroll
    for (int j = 0; j < 4; j++) {
      fa[j][0] = rdA(1, j, 0);
      fa[j][1] = rdA(1, j, 1);
    }
#pragma unroll
    for (int jn = 0; jn < 2; jn++) {
      fb0[jn][0] = rdB(1, jn, 0);
      fb0[jn][1] = rdB(1, jn, 1);
    }
    if (t0 + 2 < nt) stA(t0 + 2, 0);
    SYNC_PRE();
    QMMA(0, 0, fb0);
    SYNC_POST();
    // p6: reads B-n1(t1); stage A1(t0+2)
#pragma unroll
    for (int jn = 0; jn < 2; jn++) {
      fb1[jn][0] = rdB(1, 2 + jn, 0);
      fb1[jn][1] = rdB(1, 2 + jn, 1);
    }
    if (t0 + 2 < nt) stA(t0 + 2, 1);
    SYNC_PRE();
    QMMA(0, 1, fb1);
    SYNC_POST();
    // p7: reads A-high(t1); stage B0(t1+2) [buf1.B died after p6]
#pragma unroll
    for (int j = 0; j < 4; j++) {
      fa[j][0] = rdA(1, 4 + j, 0);
      fa[j][1] = rdA(1, 4 + j, 1);
    }
    if (t1 + 2 < nt) stB(t1 + 2, 0);
    SYNC_PRE();
    QMMA(1, 1, fb1);
    SYNC_POST();
    // p8: stage B1(t1+2); CHECKPOINT for next iter's p1 (t0+2 resident)
    if (t1 + 2 < nt) {
      stB(t1 + 2, 1);
      asm volatile("s_waitcnt vmcnt(4)" ::: "memory");
    }
    SYNC_PRE();
    QMMA(1, 0, fb0);
    SYNC_POST();
  }
  // epilogue: D[row=(quad*4+r)][col=lane&15] per 16x16 tile [m89/m91]
#pragma unroll
  for (int mi = 0; mi < 8; mi++) {
#pragma unroll
    for (int ni = 0; ni < 4; ni++) {
      int row0_ = blockIdx.x * TM + wm + mi * 16 + quad * 4;
      int col = blockIdx.y * TN + wn + ni * 16 + mrow;
      float* Cp = C + (size_t)row0_ * N + col;
      if (atom) {
#pragma unroll
        for (int r = 0; r < 4; r++) unsafeAtomicAdd(Cp + (size_t)r * N, acc[mi][ni][r]);
      } else {
#pragma unroll
        for (int r = 0; r < 4; r++) Cp[(size_t)r * N] = acc[mi][ni][r];
      }
    }
  }
}

// ---------------- row softmax: S[row][:] fp32 -> P[row][:] fp16 ----------------
__global__ __launch_bounds__(256) void softmax_rows(const float* __restrict__ S,
                                                    half_t* __restrict__ P) {
  const int row = blockIdx.x;
  const float4* Sr = (const float4*)(S + (size_t)row * SEQ);
  const int tid = threadIdx.x, lane = tid & 63, wave = tid >> 6;
  __shared__ float red[4];
  __shared__ float bc;
  float4 v[4];
  float m = -1e30f;
#pragma unroll
  for (int j = 0; j < 4; j++) {
    v[j] = Sr[tid + j * 256];
    m = fmaxf(m, fmaxf(fmaxf(v[j].x, v[j].y), fmaxf(v[j].z, v[j].w)));
  }
#pragma unroll
  for (int o = 32; o; o >>= 1) m = fmaxf(m, __shfl_xor(m, o));
  if (lane == 0) red[wave] = m;
  __syncthreads();
  if (tid == 0) bc = fmaxf(fmaxf(red[0], red[1]), fmaxf(red[2], red[3]));
  __syncthreads();
  m = bc;
  float s = 0.f;
#pragma unroll
  for (int j = 0; j < 4; j++) {
    v[j].x = __expf(v[j].x - m);
    v[j].y = __expf(v[j].y - m);
    v[j].z = __expf(v[j].z - m);
    v[j].w = __expf(v[j].w - m);
    s += v[j].x + v[j].y + v[j].z + v[j].w;
  }
#pragma unroll
  for (int o = 32; o; o >>= 1) s += __shfl_xor(s, o);
  __syncthreads();
  if (lane == 0) red[wave] = s;
  __syncthreads();
  if (tid == 0) bc = red[0] + red[1] + red[2] + red[3];
  __syncthreads();
  float r = 1.0f / bc;
  f16x4* Pr = (f16x4*)(P + (size_t)row * SEQ);
#pragma unroll
  for (int j = 0; j < 4; j++) {
    f16x4 o = {(half_t)(v[j].x * r), (half_t)(v[j].y * r), (half_t)(v[j].z * r),
               (half_t)(v[j].w * r)};
    Pr[tid + j * 256] = o;
  }
}

// ---------------- naive fp32 fallback (no workspace needed) ----------------
__global__ __launch_bounds__(256) void naive_attn(const float* __restrict__ enc,
                                                  const float* __restrict__ dec,
                                                  float* __restrict__ out) {
  const int b = blockIdx.y, t = blockIdx.x;
  const float* encb = enc + (size_t)b * SEQ * DDIM;
  const float* q = dec + ((size_t)b * SEQ + t) * DDIM;
  __shared__ float qs[DDIM];
  __shared__ float sc[SEQ];
  __shared__ float red[4];
  __shared__ float bc;
  const int tid = threadIdx.x, lane = tid & 63, wave = tid >> 6;
  for (int i = tid; i < DDIM; i += 256) qs[i] = q[i];
  __syncthreads();
  for (int e = tid; e < SEQ; e += 256) {
    const float* er = encb + (size_t)e * DDIM;
    float s = 0.f;
    for (int d = 0; d < DDIM; d += 4) {
      float4 ev = *(const float4*)(er + d);
      s += ev.x * qs[d] + ev.y * qs[d + 1] + ev.z * qs[d + 2] + ev.w * qs[d + 3];
    }
    sc[e] = s;
  }
  __syncthreads();
  float m = -1e30f;
  for (int e = tid; e < SEQ; e += 256) m = fmaxf(m, sc[e]);
#pragma unroll
  for (int o = 32; o; o >>= 1) m = fmaxf(m, __shfl_xor(m, o));
  if (lane == 0) red[wave] = m;
  __syncthreads();
  if (tid == 0) bc = fmaxf(fmaxf(red[0], red[1]), fmaxf(red[2], red[3]));
  __syncthreads();
  m = bc;
  float s = 0.f;
  for (int e = tid; e < SEQ; e += 256) {
    float p = __expf(sc[e] - m);
    sc[e] = p;
    s += p;
  }
#pragma unroll
  for (int o = 32; o; o >>= 1) s += __shfl_xor(s, o);
  __syncthreads();
  if (lane == 0) red[wave] = s;
  __syncthreads();
  if (tid == 0) bc = red[0] + red[1] + red[2] + red[3];
  __syncthreads();
  const float rinv = 1.0f / bc;
  const int d0 = tid * 4;
  float4 acc = {0.f, 0.f, 0.f, 0.f};
  for (int e = 0; e < SEQ; e++) {
    float p = sc[e];
    float4 ev = *(const float4*)(encb + (size_t)e * DDIM + d0);
    acc.x += p * ev.x;
    acc.y += p * ev.y;
    acc.z += p * ev.z;
    acc.w += p * ev.w;
  }
  float4* o4 = (float4*)(out + ((size_t)b * SEQ + t) * DDIM + d0);
  float4 res = {acc.x * rinv, acc.y * rinv, acc.z * rinv, acc.w * rinv};
  *o4 = res;
}

extern "C" void kernel_launch(void* const* d_in, const int* in_sizes, int n_in, void* d_out,
                              int out_size, void* d_ws, size_t ws_size, hipStream_t stream) {
  const float* enc = (const float*)d_in[0];
  const float* dec = (const float*)d_in[1];
  float* out = (float*)d_out;

  const size_t SZ_S = (size_t)SEQ * SEQ * 4;            // 64 MiB (one batch)
  const size_t SZ_P = (size_t)SEQ * SEQ * 2;            // 32 MiB (one batch)
  const size_t SZ_H = (size_t)NBATCH * SEQ * DDIM * 2;  // 32 MiB each
  const size_t NEED = SZ_S + SZ_P + 3 * SZ_H;           // 192 MiB (proven R0-R5)

  const int nconv = NBATCH * SEQ * DDIM / 4 / 256;  // 16384 blocks

  if (ws_size >= NEED) {
    char* w = (char*)d_ws;
    float* S = (float*)w;
    half_t* P = (half_t*)(w + SZ_S);
    half_t* decF = (half_t*)(w + SZ_S + SZ_P);
    half_t* encF = (half_t*)(w + SZ_S + SZ_P + SZ_H);
    half_t* encT = (half_t*)(w + SZ_S + SZ_P + 2 * SZ_H);

    hipMemsetAsync(out, 0, (size_t)NBATCH * SEQ * DDIM * 4, stream);
    conv_f16<<<nconv, 256, 0, stream>>>(dec, decF);
    transconv_f16<<<dim3(SEQ / 32, DDIM / 32, NBATCH), 256, 0, stream>>>(enc, encF, encT);

    for (int b = 0; b < NBATCH; b++) {
      const size_t eo = (size_t)b * SEQ * DDIM;
      // S[t][e] = dec[t]·enc[e]; grid 16x16 = 256 blocks = 1/CU
      gemm8p<<<dim3(SEQ / TM, SEQ / TN, 1), 512, 0, stream>>>(decF + eo, encF + eo, S, SEQ,
                                                              SEQ, DDIM, DDIM, 0, 0, 0, 0);
      softmax_rows<<<SEQ, 256, 0, stream>>>(S, P);
      // out[t][d] += sum_{e in chunk z} P[t][e]*encT[d][e]; split-K z=4:
      // grid 16x4x4 = 256 blocks = 1/CU, fp32 atomic epilogue
      gemm8p<<<dim3(SEQ / TM, DDIM / TN, 4), 512, 0, stream>>>(
          P, encT + (size_t)b * DDIM * SEQ, out + eo, SEQ, DDIM, SEQ, SEQ / 4, SEQ / 4,
          SEQ / 4, 0, 1);
    }
  } else {
    naive_attn<<<dim3(SEQ, NBATCH), 256, 0, stream>>>(enc, dec, out);
  }
}